// Round 6
// baseline (1201.002 us; speedup 1.0000x reference)
//
#include <hip/hip_runtime.h>
#include <hip/hip_bf16.h>
#include <stdint.h>

#define N_TOK 8192
#define DIM   1024
#define HID   4096
#define NE    8
#define CAP   17408   // 136 * 128 : worst-case padded pair slots
#define BM    128
#define BN    256
#define BK    32

typedef __bf16 bf16_t;
typedef __bf16 bf16x8 __attribute__((ext_vector_type(8)));
typedef __bf16 bf16x4 __attribute__((ext_vector_type(4)));
typedef float  f32x4  __attribute__((ext_vector_type(4)));

// ---- async global->LDS, 16B per lane. LDS dest = wave-uniform base + lane*16.
__device__ __forceinline__ void gl_lds16(const void* g, void* l) {
  __builtin_amdgcn_global_load_lds(
      reinterpret_cast<const __attribute__((address_space(1))) void*>(
          reinterpret_cast<uintptr_t>(g)),
      reinterpret_cast<__attribute__((address_space(3))) void*>(
          (uint32_t)reinterpret_cast<uintptr_t>(l)),
      16, 0, 0);
}

// ---------------- router: fp64 logits, softmax, top-2 ----------------
__global__ __launch_bounds__(256) void router_kernel(
    const float* __restrict__ x, const float* __restrict__ Wr,
    int* __restrict__ top_i, float* __restrict__ top_p, int* __restrict__ counts) {
  const int tok  = blockIdx.x * 4 + (threadIdx.x >> 6);
  const int lane = threadIdx.x & 63;
  const float* xr = x + (size_t)tok * DIM;
  double acc[NE];
  #pragma unroll
  for (int e = 0; e < NE; ++e) acc[e] = 0.0;
  for (int d = lane; d < DIM; d += 64) {
    double xv = (double)xr[d];
    #pragma unroll
    for (int e = 0; e < NE; ++e) acc[e] += xv * (double)Wr[d * NE + e];
  }
  #pragma unroll
  for (int e = 0; e < NE; ++e) {
    double v = acc[e];
    for (int off = 32; off > 0; off >>= 1) v += __shfl_down(v, off, 64);
    acc[e] = v;
  }
  if (lane == 0) {
    double m = acc[0];
    #pragma unroll
    for (int e = 1; e < NE; ++e) m = fmax(m, acc[e]);
    double p[NE]; double s = 0.0;
    #pragma unroll
    for (int e = 0; e < NE; ++e) { p[e] = exp(acc[e] - m); s += p[e]; }
    int i0 = 0; double b0 = -1.0;
    #pragma unroll
    for (int e = 0; e < NE; ++e) if (p[e] > b0) { b0 = p[e]; i0 = e; }
    int i1 = -1; double b1 = -1.0;
    #pragma unroll
    for (int e = 0; e < NE; ++e) if (e != i0 && p[e] > b1) { b1 = p[e]; i1 = e; }
    top_i[tok * 2 + 0] = i0; top_p[tok * 2 + 0] = (float)(b0 / s);
    top_i[tok * 2 + 1] = i1; top_p[tok * 2 + 1] = (float)(b1 / s);
    atomicAdd(&counts[i0], 1); atomicAdd(&counts[i1], 1);
  }
}

// ---------------- padded prefix sum over 8 experts ----------------
__global__ void offsets_kernel(const int* __restrict__ counts, int* __restrict__ off_pad) {
  if (threadIdx.x == 0) {
    int o = 0;
    #pragma unroll
    for (int e = 0; e < NE; ++e) { off_pad[e] = o; o += (counts[e] + 127) & ~127; }
    off_pad[NE] = o;
  }
}

__global__ __launch_bounds__(256) void padinit_kernel(int* __restrict__ pair_token,
                                                      float* __restrict__ pair_gate) {
  const int i = blockIdx.x * 256 + threadIdx.x;
  pair_token[i] = 0; pair_gate[i] = 0.f;
}

__global__ __launch_bounds__(256) void scatter_kernel(
    const int* __restrict__ top_i, const float* __restrict__ top_p,
    const int* __restrict__ off_pad, int* __restrict__ cursors,
    int* __restrict__ pair_token, float* __restrict__ pair_gate) {
  const int tok = blockIdx.x * 256 + threadIdx.x;
  #pragma unroll
  for (int k = 0; k < 2; ++k) {
    const int e = top_i[tok * 2 + k];
    const float p = top_p[tok * 2 + k];
    const int pos = atomicAdd(&cursors[e], 1);
    const int slot = off_pad[e] + pos;
    pair_token[slot] = tok; pair_gate[slot] = p;
  }
}

// ---------------- fp32 -> bf16 convert (x) ----------------
__global__ __launch_bounds__(256) void cvt_x_kernel(const float4* __restrict__ x4,
                                                    bf16x4* __restrict__ xb4) {
  const int i = blockIdx.x * 256 + threadIdx.x;
  const float4 v = x4[i];
  bf16x4 o;
  o[0] = (bf16_t)v.x; o[1] = (bf16_t)v.y; o[2] = (bf16_t)v.z; o[3] = (bf16_t)v.w;
  xb4[i] = o;
}

// ---------------- transpose + convert: src[e] R x C fp32 -> dst[e] C x R bf16 ----------------
__global__ __launch_bounds__(256) void transpose_cvt_kernel(
    const float* __restrict__ src, bf16_t* __restrict__ dst, int R, int C) {
  __shared__ float tile[32][33];
  const int e = blockIdx.z;
  const float* s = src + (size_t)e * R * C;
  bf16_t* d = dst + (size_t)e * R * C;
  const int c0 = blockIdx.x * 32, r0 = blockIdx.y * 32;
  const int tx = threadIdx.x, ty = threadIdx.y;   // blockDim = (32, 8)
  #pragma unroll
  for (int j = 0; j < 4; ++j)
    tile[ty + 8 * j][tx] = s[(size_t)(r0 + ty + 8 * j) * C + c0 + tx];
  __syncthreads();
  #pragma unroll
  for (int j = 0; j < 4; ++j)
    d[(size_t)(c0 + ty + 8 * j) * R + r0 + tx] = (bf16_t)tile[tx][ty + 8 * j];
}

// =================== GEMM staging layout (BM=128, BN=256, BK=32) ===================
// A-tile 128 rows x 32 k (8 KB/stage), B-tile 256 rows x 32 k (16 KB/stage);
// double-buffered -> 48 KB LDS. 16B chunk (row, kswz) at element (row*4+kswz)*8,
// holding global chunk k8 = kswz ^ ((row>>1)&3) (XOR swizzle, self-inverse).
// Staging per gl_lds16: wave covers 16 rows x 4 chunks; rsel=lane>>2,
// k8g = (lane&3) ^ ((rsel>>1)&3); LDS dest = uniform + lane*16B.
// Frag read (row=16s+cc, k8=q): kx = q ^ ((cc>>1)&3); bank-quad = 4*(cc&1)+kx
// -> per 16-lane quarter all 8 quads x 2 lanes => conflict-free.
// Wave-tile 64m x 128n: acc[4][8] (128 VGPR). 2-stage pipeline, one barrier/iter.

// ---------------- GEMM1: h = gelu(x[gather] @ W1[e]) , K = DIM ----------------
__global__ __launch_bounds__(256, 2) void gemm1_kernel(
    const bf16_t* __restrict__ xb, const bf16_t* __restrict__ w1t,
    const float* __restrict__ b1, const int* __restrict__ off_pad,
    const int* __restrict__ pair_token, bf16_t* __restrict__ hbuf) {
  __shared__ bf16_t Asm[2][BM * BK];
  __shared__ bf16_t Bsm[2][BN * BK];
  const int m0 = blockIdx.y * BM;          // grid: x = n (fastest, L3 A-sharing), y = m
  const int total = off_pad[NE];
  if (m0 >= total) return;
  int e = 0;
  while (m0 >= off_pad[e + 1]) ++e;
  const int t = threadIdx.x;
  const int lane = t & 63, wave = t >> 6;
  const int wm = wave & 1, wn = wave >> 1;
  const int n0 = blockIdx.x * BN;

  const int rsel = lane >> 2;              // 0..15 row within 16-row group
  const int k8g  = (lane & 3) ^ ((rsel >> 1) & 3);
  const bf16_t* arow[2];
  const bf16_t* brow[4];
  #pragma unroll
  for (int c = 0; c < 2; ++c) {
    const int row = c * 64 + wave * 16 + rsel;
    const int tok = pair_token[m0 + row];
    arow[c] = xb + (size_t)tok * DIM + k8g * 8;
  }
  #pragma unroll
  for (int c = 0; c < 4; ++c) {
    const int row = c * 64 + wave * 16 + rsel;
    brow[c] = w1t + ((size_t)e * HID + n0 + row) * DIM + k8g * 8;
  }

  f32x4 acc[4][8];
  #pragma unroll
  for (int i = 0; i < 4; ++i)
    #pragma unroll
    for (int j = 0; j < 8; ++j)
      #pragma unroll
      for (int r = 0; r < 4; ++r) acc[i][j][r] = 0.f;

  const int q = lane >> 4, cc = lane & 15;
  const int kx = q ^ ((cc >> 1) & 3);      // loop-invariant

  auto stage = [&](int buf, int k0) {
    bf16_t* ad = Asm[buf] + wave * 512;
    bf16_t* bd = Bsm[buf] + wave * 512;
    #pragma unroll
    for (int c = 0; c < 2; ++c) gl_lds16(arow[c] + k0, ad + c * 2048);
    #pragma unroll
    for (int c = 0; c < 4; ++c) gl_lds16(brow[c] + k0, bd + c * 2048);
  };

  stage(0, 0);
  __syncthreads();                          // tile 0 resident
  for (int kb = 0; kb < DIM / BK; ++kb) {
    if (kb + 1 < DIM / BK) stage((kb + 1) & 1, (kb + 1) * BK);
    const bf16_t* As = Asm[kb & 1];
    const bf16_t* Bs = Bsm[kb & 1];
    bf16x8 af[4], bfr[8];
    #pragma unroll
    for (int i = 0; i < 4; ++i)
      af[i]  = *(const bf16x8*)(As + ((wm * 64 + i * 16 + cc) * 4 + kx) * 8);
    #pragma unroll
    for (int i = 0; i < 8; ++i)
      bfr[i] = *(const bf16x8*)(Bs + ((wn * 128 + i * 16 + cc) * 4 + kx) * 8);
    #pragma unroll
    for (int mi = 0; mi < 4; ++mi)
      #pragma unroll
      for (int ni = 0; ni < 8; ++ni)
        acc[mi][ni] = __builtin_amdgcn_mfma_f32_16x16x32_bf16(af[mi], bfr[ni], acc[mi][ni], 0, 0, 0);
    __syncthreads();                        // drains vmcnt (tile kb+1) + lgkm
  }

  #pragma unroll
  for (int mi = 0; mi < 4; ++mi) {
    #pragma unroll
    for (int r = 0; r < 4; ++r) {
      const int row = wm * 64 + mi * 16 + q * 4 + r;
      bf16_t* op = hbuf + (size_t)(m0 + row) * HID + n0 + wn * 128 + cc;
      #pragma unroll
      for (int ni = 0; ni < 8; ++ni) {
        float v = acc[mi][ni][r] + b1[e * HID + n0 + wn * 128 + cc + ni * 16];
        float u = 0.7978845608028654f * (v + 0.044715f * v * v * v);
        float th = 1.f - 2.f / (__expf(2.f * u) + 1.f);
        op[ni * 16] = (bf16_t)(0.5f * v * (1.f + th));
      }
    }
  }
}

// ---------------- GEMM2: out[token] += gate * (h @ W2[e] + b2) , K = HID ----------------
__global__ __launch_bounds__(256, 2) void gemm2_kernel(
    const bf16_t* __restrict__ hbuf, const bf16_t* __restrict__ w2t,
    const float* __restrict__ b2, const int* __restrict__ off_pad,
    const int* __restrict__ pair_token, const float* __restrict__ pair_gate,
    float* __restrict__ dout) {
  __shared__ bf16_t Asm[2][BM * BK];
  __shared__ bf16_t Bsm[2][BN * BK];
  const int m0 = blockIdx.y * BM;          // grid: x = n (fastest, L3 A-sharing), y = m
  const int total = off_pad[NE];
  if (m0 >= total) return;
  int e = 0;
  while (m0 >= off_pad[e + 1]) ++e;
  const int t = threadIdx.x;
  const int lane = t & 63, wave = t >> 6;
  const int wm = wave & 1, wn = wave >> 1;
  const int n0 = blockIdx.x * BN;

  const int rsel = lane >> 2;
  const int k8g  = (lane & 3) ^ ((rsel >> 1) & 3);
  const bf16_t* arow[2];
  const bf16_t* brow[4];
  #pragma unroll
  for (int c = 0; c < 2; ++c) {
    const int row = c * 64 + wave * 16 + rsel;
    arow[c] = hbuf + (size_t)(m0 + row) * HID + k8g * 8;
  }
  #pragma unroll
  for (int c = 0; c < 4; ++c) {
    const int row = c * 64 + wave * 16 + rsel;
    brow[c] = w2t + ((size_t)e * DIM + n0 + row) * HID + k8g * 8;
  }

  f32x4 acc[4][8];
  #pragma unroll
  for (int i = 0; i < 4; ++i)
    #pragma unroll
    for (int j = 0; j < 8; ++j)
      #pragma unroll
      for (int r = 0; r < 4; ++r) acc[i][j][r] = 0.f;

  const int q = lane >> 4, cc = lane & 15;
  const int kx = q ^ ((cc >> 1) & 3);

  auto stage = [&](int buf, int k0) {
    bf16_t* ad = Asm[buf] + wave * 512;
    bf16_t* bd = Bsm[buf] + wave * 512;
    #pragma unroll
    for (int c = 0; c < 2; ++c) gl_lds16(arow[c] + k0, ad + c * 2048);
    #pragma unroll
    for (int c = 0; c < 4; ++c) gl_lds16(brow[c] + k0, bd + c * 2048);
  };

  stage(0, 0);
  __syncthreads();
  for (int kb = 0; kb < HID / BK; ++kb) {
    if (kb + 1 < HID / BK) stage((kb + 1) & 1, (kb + 1) * BK);
    const bf16_t* As = Asm[kb & 1];
    const bf16_t* Bs = Bsm[kb & 1];
    bf16x8 af[4], bfr[8];
    #pragma unroll
    for (int i = 0; i < 4; ++i)
      af[i]  = *(const bf16x8*)(As + ((wm * 64 + i * 16 + cc) * 4 + kx) * 8);
    #pragma unroll
    for (int i = 0; i < 8; ++i)
      bfr[i] = *(const bf16x8*)(Bs + ((wn * 128 + i * 16 + cc) * 4 + kx) * 8);
    #pragma unroll
    for (int mi = 0; mi < 4; ++mi)
      #pragma unroll
      for (int ni = 0; ni < 8; ++ni)
        acc[mi][ni] = __builtin_amdgcn_mfma_f32_16x16x32_bf16(af[mi], bfr[ni], acc[mi][ni], 0, 0, 0);
    __syncthreads();
  }

  #pragma unroll
  for (int mi = 0; mi < 4; ++mi) {
    #pragma unroll
    for (int r = 0; r < 4; ++r) {
      const int row = wm * 64 + mi * 16 + q * 4 + r;
      const int slot = m0 + row;
      const float gate = pair_gate[slot];
      if (gate != 0.f) {
        const int tok = pair_token[slot];
        float* op = dout + (size_t)tok * DIM + n0 + wn * 128 + cc;
        #pragma unroll
        for (int ni = 0; ni < 8; ++ni) {
          float v = acc[mi][ni][r] + b2[e * DIM + n0 + wn * 128 + cc + ni * 16];
          atomicAdd(op + ni * 16, gate * v);
        }
      }
    }
  }
}

extern "C" void kernel_launch(void* const* d_in, const int* in_sizes, int n_in,
                              void* d_out, int out_size, void* d_ws, size_t ws_size,
                              hipStream_t stream) {
  const float* x  = (const float*)d_in[0];
  const float* Wr = (const float*)d_in[1];
  const float* W1 = (const float*)d_in[2];
  const float* b1 = (const float*)d_in[3];
  const float* W2 = (const float*)d_in[4];
  const float* b2 = (const float*)d_in[5];
  float* out = (float*)d_out;

  char* ws = (char*)d_ws;
  size_t off = 0;
  auto alloc = [&](size_t bytes) -> char* {
    char* p = ws + off; off = (off + bytes + 255) & ~(size_t)255; return p;
  };
  int*    meta       = (int*)alloc(64);           // counts[8] + cursors[8]
  int*    counts     = meta;
  int*    cursors    = meta + 8;
  int*    off_pad    = (int*)alloc(16 * 4);
  int*    top_i      = (int*)alloc((size_t)N_TOK * 2 * 4);
  float*  top_p      = (float*)alloc((size_t)N_TOK * 2 * 4);
  int*    pair_token = (int*)alloc((size_t)CAP * 4);
  float*  pair_gate  = (float*)alloc((size_t)CAP * 4);
  bf16_t* xb         = (bf16_t*)alloc((size_t)N_TOK * DIM * 2);
  bf16_t* w1t        = (bf16_t*)alloc((size_t)NE * DIM * HID * 2);
  bf16_t* w2t        = (bf16_t*)alloc((size_t)NE * DIM * HID * 2);
  bf16_t* hbuf       = (bf16_t*)alloc((size_t)CAP * HID * 2);
  if (off > ws_size) {  // visible failure instead of memory corruption
    hipMemsetAsync(out, 0, (size_t)N_TOK * DIM * 4, stream);
    return;
  }

  hipMemsetAsync(meta, 0, 64, stream);
  hipMemsetAsync(out, 0, (size_t)N_TOK * DIM * 4, stream);
  router_kernel<<<N_TOK / 4, 256, 0, stream>>>(x, Wr, top_i, top_p, counts);
  offsets_kernel<<<1, 64, 0, stream>>>(counts, off_pad);
  padinit_kernel<<<CAP / 256, 256, 0, stream>>>(pair_token, pair_gate);
  scatter_kernel<<<N_TOK / 256, 256, 0, stream>>>(top_i, top_p, off_pad, cursors,
                                                  pair_token, pair_gate);
  cvt_x_kernel<<<(N_TOK * DIM / 4) / 256, 256, 0, stream>>>((const float4*)x, (bf16x4*)xb);
  transpose_cvt_kernel<<<dim3(HID / 32, DIM / 32, NE), dim3(32, 8), 0, stream>>>(W1, w1t, DIM, HID);
  transpose_cvt_kernel<<<dim3(DIM / 32, HID / 32, NE), dim3(32, 8), 0, stream>>>(W2, w2t, HID, DIM);
  gemm1_kernel<<<dim3(HID / BN, CAP / BM), 256, 0, stream>>>(xb, w1t, b1, off_pad, pair_token, hbuf);
  gemm2_kernel<<<dim3(DIM / BN, CAP / BM), 256, 0, stream>>>(hbuf, w2t, b2, off_pad,
                                                             pair_token, pair_gate, out);
}

// Round 7
// 1072.364 us; speedup vs baseline: 1.1200x; 1.1200x over previous
//
#include <hip/hip_runtime.h>
#include <hip/hip_bf16.h>
#include <stdint.h>

#define N_TOK 8192
#define DIM   1024
#define HID   4096
#define NE    8
#define CAP   17408   // 136 * 128 : worst-case padded pair slots
#define BM    128
#define BN    128
#define BK    32
#define NB    3       // LDS ring depth

typedef __bf16 bf16_t;
typedef __bf16 bf16x8 __attribute__((ext_vector_type(8)));
typedef __bf16 bf16x4 __attribute__((ext_vector_type(4)));
typedef float  f32x4  __attribute__((ext_vector_type(4)));

// ---- async global->LDS, 16B per lane. LDS dest = wave-uniform base + lane*16.
__device__ __forceinline__ void gl_lds16(const void* g, void* l) {
  __builtin_amdgcn_global_load_lds(
      reinterpret_cast<const __attribute__((address_space(1))) void*>(
          reinterpret_cast<uintptr_t>(g)),
      reinterpret_cast<__attribute__((address_space(3))) void*>(
          (uint32_t)reinterpret_cast<uintptr_t>(l)),
      16, 0, 0);
}

// raw barrier: NO implicit vmcnt(0) drain (unlike __syncthreads)
__device__ __forceinline__ void wave_barrier() {
  asm volatile("" ::: "memory");
  __builtin_amdgcn_s_barrier();
  asm volatile("" ::: "memory");
}

// ---------------- router: fp64 logits, softmax, top-2 ----------------
__global__ __launch_bounds__(256) void router_kernel(
    const float* __restrict__ x, const float* __restrict__ Wr,
    int* __restrict__ top_i, float* __restrict__ top_p, int* __restrict__ counts) {
  const int tok  = blockIdx.x * 4 + (threadIdx.x >> 6);
  const int lane = threadIdx.x & 63;
  const float* xr = x + (size_t)tok * DIM;
  double acc[NE];
  #pragma unroll
  for (int e = 0; e < NE; ++e) acc[e] = 0.0;
  for (int d = lane; d < DIM; d += 64) {
    double xv = (double)xr[d];
    #pragma unroll
    for (int e = 0; e < NE; ++e) acc[e] += xv * (double)Wr[d * NE + e];
  }
  #pragma unroll
  for (int e = 0; e < NE; ++e) {
    double v = acc[e];
    for (int off = 32; off > 0; off >>= 1) v += __shfl_down(v, off, 64);
    acc[e] = v;
  }
  if (lane == 0) {
    double m = acc[0];
    #pragma unroll
    for (int e = 1; e < NE; ++e) m = fmax(m, acc[e]);
    double p[NE]; double s = 0.0;
    #pragma unroll
    for (int e = 0; e < NE; ++e) { p[e] = exp(acc[e] - m); s += p[e]; }
    int i0 = 0; double b0 = -1.0;
    #pragma unroll
    for (int e = 0; e < NE; ++e) if (p[e] > b0) { b0 = p[e]; i0 = e; }
    int i1 = -1; double b1 = -1.0;
    #pragma unroll
    for (int e = 0; e < NE; ++e) if (e != i0 && p[e] > b1) { b1 = p[e]; i1 = e; }
    top_i[tok * 2 + 0] = i0; top_p[tok * 2 + 0] = (float)(b0 / s);
    top_i[tok * 2 + 1] = i1; top_p[tok * 2 + 1] = (float)(b1 / s);
    atomicAdd(&counts[i0], 1); atomicAdd(&counts[i1], 1);
  }
}

// ---------------- padded prefix sum over 8 experts ----------------
__global__ void offsets_kernel(const int* __restrict__ counts, int* __restrict__ off_pad) {
  if (threadIdx.x == 0) {
    int o = 0;
    #pragma unroll
    for (int e = 0; e < NE; ++e) { off_pad[e] = o; o += (counts[e] + 127) & ~127; }
    off_pad[NE] = o;
  }
}

__global__ __launch_bounds__(256) void padinit_kernel(int* __restrict__ pair_token,
                                                      float* __restrict__ pair_gate) {
  const int i = blockIdx.x * 256 + threadIdx.x;
  pair_token[i] = 0; pair_gate[i] = 0.f;
}

__global__ __launch_bounds__(256) void scatter_kernel(
    const int* __restrict__ top_i, const float* __restrict__ top_p,
    const int* __restrict__ off_pad, int* __restrict__ cursors,
    int* __restrict__ pair_token, float* __restrict__ pair_gate) {
  const int tok = blockIdx.x * 256 + threadIdx.x;
  #pragma unroll
  for (int k = 0; k < 2; ++k) {
    const int e = top_i[tok * 2 + k];
    const float p = top_p[tok * 2 + k];
    const int pos = atomicAdd(&cursors[e], 1);
    const int slot = off_pad[e] + pos;
    pair_token[slot] = tok; pair_gate[slot] = p;
  }
}

// ---------------- fp32 -> bf16 convert (x) ----------------
__global__ __launch_bounds__(256) void cvt_x_kernel(const float4* __restrict__ x4,
                                                    bf16x4* __restrict__ xb4) {
  const int i = blockIdx.x * 256 + threadIdx.x;
  const float4 v = x4[i];
  bf16x4 o;
  o[0] = (bf16_t)v.x; o[1] = (bf16_t)v.y; o[2] = (bf16_t)v.z; o[3] = (bf16_t)v.w;
  xb4[i] = o;
}

// ---------------- transpose + convert: src[e] R x C fp32 -> dst[e] C x R bf16 ----------------
__global__ __launch_bounds__(256) void transpose_cvt_kernel(
    const float* __restrict__ src, bf16_t* __restrict__ dst, int R, int C) {
  __shared__ float tile[32][33];
  const int e = blockIdx.z;
  const float* s = src + (size_t)e * R * C;
  bf16_t* d = dst + (size_t)e * R * C;
  const int c0 = blockIdx.x * 32, r0 = blockIdx.y * 32;
  const int tx = threadIdx.x, ty = threadIdx.y;   // blockDim = (32, 8)
  #pragma unroll
  for (int j = 0; j < 4; ++j)
    tile[ty + 8 * j][tx] = s[(size_t)(r0 + ty + 8 * j) * C + c0 + tx];
  __syncthreads();
  #pragma unroll
  for (int j = 0; j < 4; ++j)
    d[(size_t)(c0 + ty + 8 * j) * R + r0 + tx] = (bf16_t)tile[tx][ty + 8 * j];
}

// =================== GEMM staging (BK=32 swizzle, 3-deep ring) ===================
// LDS chunk (row, kswz) at element (row*4+kswz)*8, global k8 = kswz ^ ((row>>1)&3).
// Staging: rsel=lane>>2, k8g=(lane&3)^((rsel>>1)&3); dest = uniform + lane*16B.
// Frag read: kx = q ^ ((cc>>1)&3); bank-quad 4*(cc&1)+kx -> 8 quads x 2 lanes, free.
// Pipeline: ring of NB=3 buffers. Iter kb: issue stage(kb+2); s_waitcnt vmcnt(8)
// (stage kb landed; kb+1/kb+2 = 8 loads REMAIN IN FLIGHT across the barrier);
// raw s_barrier; compute(kb); raw s_barrier. Distance(write kb+2, read kb) = 2
// (!= 0 mod 3) and the post-compute barrier bounds wave skew to one interval,
// so the ring is race-free. 48 KB LDS -> 3 blocks/CU.

#define GEMM_PIPE_LOOP(NIT)                                                     \
  stage(0, 0);                                                                  \
  stage(1, BK);                                                                 \
  for (int kb = 0; kb < (NIT); ++kb) {                                          \
    if (kb + 2 < (NIT)) {                                                       \
      stage((kb + 2) % NB, (kb + 2) * BK);                                      \
      asm volatile("s_waitcnt vmcnt(8)" ::: "memory");                          \
    } else if (kb + 1 < (NIT)) {                                                \
      asm volatile("s_waitcnt vmcnt(4)" ::: "memory");                          \
    } else {                                                                    \
      asm volatile("s_waitcnt vmcnt(0)" ::: "memory");                          \
    }                                                                           \
    wave_barrier();                                                             \
    const bf16_t* As = Asm[kb % NB];                                            \
    const bf16_t* Bs = Bsm[kb % NB];                                            \
    bf16x8 af[4], bfr[4];                                                       \
    _Pragma("unroll")                                                           \
    for (int i = 0; i < 4; ++i) {                                               \
      af[i]  = *(const bf16x8*)(As + ((wm * 64 + i * 16 + cc) * 4 + kx) * 8);   \
      bfr[i] = *(const bf16x8*)(Bs + ((wn * 64 + i * 16 + cc) * 4 + kx) * 8);   \
    }                                                                           \
    _Pragma("unroll")                                                           \
    for (int mi = 0; mi < 4; ++mi)                                              \
      _Pragma("unroll")                                                         \
      for (int ni = 0; ni < 4; ++ni)                                            \
        acc[mi][ni] = __builtin_amdgcn_mfma_f32_16x16x32_bf16(af[mi], bfr[ni],  \
                                                              acc[mi][ni], 0, 0, 0); \
    wave_barrier();                                                             \
  }

// ---------------- GEMM1: h = gelu(x[gather] @ W1[e]) , K = DIM ----------------
__global__ __launch_bounds__(256, 3) void gemm1_kernel(
    const bf16_t* __restrict__ xb, const bf16_t* __restrict__ w1t,
    const float* __restrict__ b1, const int* __restrict__ off_pad,
    const int* __restrict__ pair_token, bf16_t* __restrict__ hbuf) {
  __shared__ bf16_t Asm[NB][BM * BK];
  __shared__ bf16_t Bsm[NB][BK * BN];
  const int m0 = blockIdx.y * BM;          // grid: x = n (adjacent share A), y = m
  const int total = off_pad[NE];
  if (m0 >= total) return;
  int e = 0;
  while (m0 >= off_pad[e + 1]) ++e;
  const int t = threadIdx.x;
  const int lane = t & 63, wave = t >> 6;
  const int wm = wave & 1, wn = wave >> 1;
  const int n0 = blockIdx.x * BN;

  const int rsel = lane >> 2;              // 0..15 row within 16-row group
  const int k8g  = (lane & 3) ^ ((rsel >> 1) & 3);
  const bf16_t* arow[2];
  const bf16_t* brow[2];
  #pragma unroll
  for (int c = 0; c < 2; ++c) {
    const int row = c * 64 + wave * 16 + rsel;
    const int tok = pair_token[m0 + row];
    arow[c] = xb + (size_t)tok * DIM + k8g * 8;
    brow[c] = w1t + ((size_t)e * HID + n0 + row) * DIM + k8g * 8;
  }

  f32x4 acc[4][4];
  #pragma unroll
  for (int i = 0; i < 4; ++i)
    #pragma unroll
    for (int j = 0; j < 4; ++j)
      #pragma unroll
      for (int r = 0; r < 4; ++r) acc[i][j][r] = 0.f;

  const int q = lane >> 4, cc = lane & 15;
  const int kx = q ^ ((cc >> 1) & 3);      // loop-invariant

  auto stage = [&](int buf, int k0) {
    bf16_t* ad = Asm[buf] + wave * 512;
    bf16_t* bd = Bsm[buf] + wave * 512;
    #pragma unroll
    for (int c = 0; c < 2; ++c) {
      gl_lds16(arow[c] + k0, ad + c * 2048);
      gl_lds16(brow[c] + k0, bd + c * 2048);
    }
  };

  GEMM_PIPE_LOOP(DIM / BK)

  #pragma unroll
  for (int mi = 0; mi < 4; ++mi) {
    #pragma unroll
    for (int r = 0; r < 4; ++r) {
      const int row = wm * 64 + mi * 16 + q * 4 + r;
      bf16_t* op = hbuf + (size_t)(m0 + row) * HID + n0 + wn * 64 + cc;
      #pragma unroll
      for (int ni = 0; ni < 4; ++ni) {
        float v = acc[mi][ni][r] + b1[e * HID + n0 + wn * 64 + cc + ni * 16];
        float u = 0.7978845608028654f * (v + 0.044715f * v * v * v);
        float th = 1.f - 2.f / (__expf(2.f * u) + 1.f);
        op[ni * 16] = (bf16_t)(0.5f * v * (1.f + th));
      }
    }
  }
}

// ---------------- GEMM2: out[token] += gate * (h @ W2[e] + b2) , K = HID ----------------
__global__ __launch_bounds__(256, 3) void gemm2_kernel(
    const bf16_t* __restrict__ hbuf, const bf16_t* __restrict__ w2t,
    const float* __restrict__ b2, const int* __restrict__ off_pad,
    const int* __restrict__ pair_token, const float* __restrict__ pair_gate,
    float* __restrict__ dout) {
  __shared__ bf16_t Asm[NB][BM * BK];
  __shared__ bf16_t Bsm[NB][BK * BN];
  const int m0 = blockIdx.y * BM;          // grid: x = n (adjacent share A), y = m
  const int total = off_pad[NE];
  if (m0 >= total) return;
  int e = 0;
  while (m0 >= off_pad[e + 1]) ++e;
  const int t = threadIdx.x;
  const int lane = t & 63, wave = t >> 6;
  const int wm = wave & 1, wn = wave >> 1;
  const int n0 = blockIdx.x * BN;

  const int rsel = lane >> 2;
  const int k8g  = (lane & 3) ^ ((rsel >> 1) & 3);
  const bf16_t* arow[2];
  const bf16_t* brow[2];
  #pragma unroll
  for (int c = 0; c < 2; ++c) {
    const int row = c * 64 + wave * 16 + rsel;
    arow[c] = hbuf + (size_t)(m0 + row) * HID + k8g * 8;
    brow[c] = w2t + ((size_t)e * DIM + n0 + row) * HID + k8g * 8;
  }

  f32x4 acc[4][4];
  #pragma unroll
  for (int i = 0; i < 4; ++i)
    #pragma unroll
    for (int j = 0; j < 4; ++j)
      #pragma unroll
      for (int r = 0; r < 4; ++r) acc[i][j][r] = 0.f;

  const int q = lane >> 4, cc = lane & 15;
  const int kx = q ^ ((cc >> 1) & 3);

  auto stage = [&](int buf, int k0) {
    bf16_t* ad = Asm[buf] + wave * 512;
    bf16_t* bd = Bsm[buf] + wave * 512;
    #pragma unroll
    for (int c = 0; c < 2; ++c) {
      gl_lds16(arow[c] + k0, ad + c * 2048);
      gl_lds16(brow[c] + k0, bd + c * 2048);
    }
  };

  GEMM_PIPE_LOOP(HID / BK)

  #pragma unroll
  for (int mi = 0; mi < 4; ++mi) {
    #pragma unroll
    for (int r = 0; r < 4; ++r) {
      const int row = wm * 64 + mi * 16 + q * 4 + r;
      const int slot = m0 + row;
      const float gate = pair_gate[slot];
      if (gate != 0.f) {
        const int tok = pair_token[slot];
        float* op = dout + (size_t)tok * DIM + n0 + wn * 64 + cc;
        #pragma unroll
        for (int ni = 0; ni < 4; ++ni) {
          float v = acc[mi][ni][r] + b2[e * DIM + n0 + wn * 64 + cc + ni * 16];
          atomicAdd(op + ni * 16, gate * v);
        }
      }
    }
  }
}

extern "C" void kernel_launch(void* const* d_in, const int* in_sizes, int n_in,
                              void* d_out, int out_size, void* d_ws, size_t ws_size,
                              hipStream_t stream) {
  const float* x  = (const float*)d_in[0];
  const float* Wr = (const float*)d_in[1];
  const float* W1 = (const float*)d_in[2];
  const float* b1 = (const float*)d_in[3];
  const float* W2 = (const float*)d_in[4];
  const float* b2 = (const float*)d_in[5];
  float* out = (float*)d_out;

  char* ws = (char*)d_ws;
  size_t off = 0;
  auto alloc = [&](size_t bytes) -> char* {
    char* p = ws + off; off = (off + bytes + 255) & ~(size_t)255; return p;
  };
  int*    meta       = (int*)alloc(64);           // counts[8] + cursors[8]
  int*    counts     = meta;
  int*    cursors    = meta + 8;
  int*    off_pad    = (int*)alloc(16 * 4);
  int*    top_i      = (int*)alloc((size_t)N_TOK * 2 * 4);
  float*  top_p      = (float*)alloc((size_t)N_TOK * 2 * 4);
  int*    pair_token = (int*)alloc((size_t)CAP * 4);
  float*  pair_gate  = (float*)alloc((size_t)CAP * 4);
  bf16_t* xb         = (bf16_t*)alloc((size_t)N_TOK * DIM * 2);
  bf16_t* w1t        = (bf16_t*)alloc((size_t)NE * DIM * HID * 2);
  bf16_t* w2t        = (bf16_t*)alloc((size_t)NE * DIM * HID * 2);
  bf16_t* hbuf       = (bf16_t*)alloc((size_t)CAP * HID * 2);
  if (off > ws_size) {  // visible failure instead of memory corruption
    hipMemsetAsync(out, 0, (size_t)N_TOK * DIM * 4, stream);
    return;
  }

  hipMemsetAsync(meta, 0, 64, stream);
  hipMemsetAsync(out, 0, (size_t)N_TOK * DIM * 4, stream);
  router_kernel<<<N_TOK / 4, 256, 0, stream>>>(x, Wr, top_i, top_p, counts);
  offsets_kernel<<<1, 64, 0, stream>>>(counts, off_pad);
  padinit_kernel<<<CAP / 256, 256, 0, stream>>>(pair_token, pair_gate);
  scatter_kernel<<<N_TOK / 256, 256, 0, stream>>>(top_i, top_p, off_pad, cursors,
                                                  pair_token, pair_gate);
  cvt_x_kernel<<<(N_TOK * DIM / 4) / 256, 256, 0, stream>>>((const float4*)x, (bf16x4*)xb);
  transpose_cvt_kernel<<<dim3(HID / 32, DIM / 32, NE), dim3(32, 8), 0, stream>>>(W1, w1t, DIM, HID);
  transpose_cvt_kernel<<<dim3(DIM / 32, HID / 32, NE), dim3(32, 8), 0, stream>>>(W2, w2t, HID, DIM);
  gemm1_kernel<<<dim3(HID / BN, CAP / BM), 256, 0, stream>>>(xb, w1t, b1, off_pad, pair_token, hbuf);
  gemm2_kernel<<<dim3(DIM / BN, CAP / BM), 256, 0, stream>>>(hbuf, w2t, b2, off_pad,
                                                             pair_token, pair_gate, out);
}